// Round 1
// baseline (2500.332 us; speedup 1.0000x reference)
//
#include <hip/hip_runtime.h>
#include <math.h>

#define BN_EPS 1e-5f

// ---------------------------------------------------------------------------
// pooled[bc] = mean over 128x128 of in[bc][:][:]
// ---------------------------------------------------------------------------
__global__ void pool_kernel(const float* __restrict__ in, float* __restrict__ pooled) {
    const int bc = blockIdx.x;
    const float* p = in + (size_t)bc * (128 * 128);
    float s = 0.f;
    for (int i = threadIdx.x; i < 128 * 128; i += 256) s += p[i];
    // wave (64-lane) reduce
    for (int off = 32; off > 0; off >>= 1) s += __shfl_down(s, off);
    __shared__ float ls[4];
    const int lane = threadIdx.x & 63, wv = threadIdx.x >> 6;
    if (lane == 0) ls[wv] = s;
    __syncthreads();
    if (threadIdx.x == 0) {
        pooled[bc] = (ls[0] + ls[1] + ls[2] + ls[3]) * (1.f / 16384.f);
    }
}

// ---------------------------------------------------------------------------
// rw[b*3+e] = sigmoid(sum_c pooled[b*C+c] * fc_w[e*C+c] + fc_b[e])
// ---------------------------------------------------------------------------
__global__ void route_kernel(const float* __restrict__ pooled,
                             const float* __restrict__ fc_w,
                             const float* __restrict__ fc_b,
                             float* __restrict__ rw, int C) {
    const int idx = threadIdx.x;  // need 48
    if (idx < 16 * 3) {
        const int b = idx / 3, e = idx % 3;
        float s = fc_b[e];
        for (int c = 0; c < C; ++c) s += pooled[b * C + c] * fc_w[e * C + c];
        rw[idx] = 1.f / (1.f + expf(-s));
    }
}

// ---------------------------------------------------------------------------
// Fused per-sample conv3x3(pad1) + bias + BN(eval) + ReLU.
//   in : [16, CIN, 128, 128]
//   w  : [3, 128, CIN, 3, 3]   (expert weights, mixed on the fly with rw)
//   out: [16, 128, 128, 128]
// Block: 256 threads -> tile of 16 output channels x (16 rows x 64 cols).
// Each thread: 1 row x 4 cols (stride 16) x 16 channels = 64 accumulators.
// ---------------------------------------------------------------------------
template <int CIN>
__global__ __launch_bounds__(256, 2)
void conv_bn_relu_kernel(const float* __restrict__ in,
                         const float* __restrict__ w,
                         const float* __restrict__ bias,
                         const float* __restrict__ rw,
                         const float* __restrict__ bng, const float* __restrict__ bnb,
                         const float* __restrict__ bnm, const float* __restrict__ bnv,
                         float* __restrict__ out) {
    const int b    = blockIdx.z;        // 0..15
    const int cog  = blockIdx.y;        // 0..7  -> output channels cog*16..+15
    const int tile = blockIdx.x;        // 0..15 -> th = tile>>1, tw = tile&1
    const int h0 = (tile >> 1) * 16;
    const int w0 = (tile & 1) * 64;

    // LDS: input halo tile rows padded to 72 floats (bank offsets {0,8,16,24}
    // per wave -> exactly 2-way aliasing, free on CDNA4).
    __shared__ float sIn[18][72];
    __shared__ float sW[16][9];

    const int tid = threadIdx.x;
    const int r   = tid >> 4;   // 0..15 tile row
    const int c0  = tid & 15;   // 0..15 base col

    float acc[16][4];
#pragma unroll
    for (int i = 0; i < 16; ++i)
#pragma unroll
        for (int j = 0; j < 4; ++j) acc[i][j] = 0.f;

    const float r0 = rw[b * 3 + 0], r1 = rw[b * 3 + 1], r2 = rw[b * 3 + 2];
    const float* inb = in + (size_t)b * CIN * 16384;

    for (int ci = 0; ci < CIN; ++ci) {
        __syncthreads();
        // ---- stage input halo tile 18 x 66 (zero-padded at borders) ----
        const float* inc = inb + (size_t)ci * 16384;
        for (int idx = tid; idx < 18 * 66; idx += 256) {
            const int rr = idx / 66, cc = idx % 66;
            const int gh = h0 - 1 + rr, gw = w0 - 1 + cc;
            float v = 0.f;
            if ((unsigned)gh < 128u && (unsigned)gw < 128u) v = inc[gh * 128 + gw];
            sIn[rr][cc] = v;
        }
        // ---- stage mixed weights 16 x 9 for this ci ----
        if (tid < 144) {
            const int co = tid / 9, k = tid % 9;
            const size_t o = ((size_t)(cog * 16 + co) * CIN + ci) * 9 + k;
            sW[co][k] = r0 * w[o]
                      + r1 * w[o + (size_t)128 * CIN * 9]
                      + r2 * w[o + (size_t)2 * 128 * CIN * 9];
        }
        __syncthreads();
        // ---- compute ----
#pragma unroll
        for (int dy = 0; dy < 3; ++dy) {
#pragma unroll
            for (int dx = 0; dx < 3; ++dx) {
                const float iv0 = sIn[r + dy][c0 + dx];
                const float iv1 = sIn[r + dy][c0 + 16 + dx];
                const float iv2 = sIn[r + dy][c0 + 32 + dx];
                const float iv3 = sIn[r + dy][c0 + 48 + dx];
                const int k = dy * 3 + dx;
#pragma unroll
                for (int co = 0; co < 16; ++co) {
                    const float wv = sW[co][k];
                    acc[co][0] += iv0 * wv;
                    acc[co][1] += iv1 * wv;
                    acc[co][2] += iv2 * wv;
                    acc[co][3] += iv3 * wv;
                }
            }
        }
    }

    // ---- epilogue: +bias, BN (eval), ReLU, store ----
#pragma unroll
    for (int co = 0; co < 16; ++co) {
        const int oc = cog * 16 + co;
        const float inv = bng[oc] * rsqrtf(bnv[oc] + BN_EPS);
        const float sh  = bnb[oc] - bnm[oc] * inv;
        const float bi  = bias[oc];
        float* op = out + (((size_t)(b * 128 + oc) * 128 + (h0 + r)) * 128) + w0 + c0;
#pragma unroll
        for (int j = 0; j < 4; ++j) {
            float v = (acc[co][j] + bi) * inv + sh;
            op[16 * j] = v > 0.f ? v : 0.f;
        }
    }
}

// ---------------------------------------------------------------------------
extern "C" void kernel_launch(void* const* d_in, const int* in_sizes, int n_in,
                              void* d_out, int out_size, void* d_ws, size_t ws_size,
                              hipStream_t stream) {
    const float* x     = (const float*)d_in[0];
    const float* w1    = (const float*)d_in[1];
    const float* b1    = (const float*)d_in[2];
    const float* fc1_w = (const float*)d_in[3];
    const float* fc1_b = (const float*)d_in[4];
    const float* bn1g  = (const float*)d_in[5];
    const float* bn1b  = (const float*)d_in[6];
    const float* bn1m  = (const float*)d_in[7];
    const float* bn1v  = (const float*)d_in[8];
    const float* w2    = (const float*)d_in[9];
    const float* b2    = (const float*)d_in[10];
    const float* fc2_w = (const float*)d_in[11];
    const float* fc2_b = (const float*)d_in[12];
    const float* bn2g  = (const float*)d_in[13];
    const float* bn2b  = (const float*)d_in[14];
    const float* bn2m  = (const float*)d_in[15];
    const float* bn2v  = (const float*)d_in[16];

    float* out = (float*)d_out;

    // workspace layout
    float* h      = (float*)d_ws;            // 16*128*128*128 = 33,554,432 floats
    float* pooled = h + 33554432;            // up to 16*128 = 2048 floats
    float* rw1    = pooled + 2048;           // 48 floats
    float* rw2    = rw1 + 48;                // 48 floats

    // ---- layer 1 ----
    pool_kernel<<<16 * 64, 256, 0, stream>>>(x, pooled);
    route_kernel<<<1, 64, 0, stream>>>(pooled, fc1_w, fc1_b, rw1, 64);
    conv_bn_relu_kernel<64><<<dim3(16, 8, 16), 256, 0, stream>>>(
        x, w1, b1, rw1, bn1g, bn1b, bn1m, bn1v, h);

    // ---- layer 2 ----
    pool_kernel<<<16 * 128, 256, 0, stream>>>(h, pooled);
    route_kernel<<<1, 64, 0, stream>>>(pooled, fc2_w, fc2_b, rw2, 128);
    conv_bn_relu_kernel<128><<<dim3(16, 8, 16), 256, 0, stream>>>(
        h, w2, b2, rw2, bn2g, bn2b, bn2m, bn2v, out);
}

// Round 2
// 394.440 us; speedup vs baseline: 6.3389x; 6.3389x over previous
//
#include <hip/hip_runtime.h>
#include <math.h>

#define BN_EPS 1e-5f

typedef short bf16x8 __attribute__((ext_vector_type(8)));
typedef float f32x4 __attribute__((ext_vector_type(4)));
typedef unsigned short ushort8v __attribute__((ext_vector_type(8)));
typedef unsigned int uint;
typedef unsigned short ushort;

__device__ inline ushort f2bf(float f) {           // RNE float->bf16
    uint u = __float_as_uint(f);
    uint r = u + 0x7FFFu + ((u >> 16) & 1u);
    return (ushort)(r >> 16);
}
__device__ inline float bf2f(ushort u) { return __uint_as_float(((uint)u) << 16); }

// ---------------------------------------------------------------------------
// pooled[bc] = mean over 128x128 of in[bc][:][:]   (fp32 NCHW input)
// ---------------------------------------------------------------------------
__global__ void pool_kernel(const float* __restrict__ in, float* __restrict__ pooled) {
    const int bc = blockIdx.x;
    const float* p = in + (size_t)bc * (128 * 128);
    float s = 0.f;
    for (int i = threadIdx.x; i < 128 * 128; i += 256) s += p[i];
    for (int off = 32; off > 0; off >>= 1) s += __shfl_down(s, off);
    __shared__ float ls[4];
    const int lane = threadIdx.x & 63, wv = threadIdx.x >> 6;
    if (lane == 0) ls[wv] = s;
    __syncthreads();
    if (threadIdx.x == 0) pooled[bc] = (ls[0] + ls[1] + ls[2] + ls[3]) * (1.f / 16384.f);
}

// ---------------------------------------------------------------------------
// rw[b*3+e] = sigmoid(dot(pooled[b], fc_w[e]) + fc_b[e])
// ---------------------------------------------------------------------------
__global__ void route_kernel(const float* __restrict__ pooled,
                             const float* __restrict__ fc_w,
                             const float* __restrict__ fc_b,
                             float* __restrict__ rw, int C) {
    const int idx = threadIdx.x;
    if (idx < 16 * 3) {
        const int b = idx / 3, e = idx % 3;
        float s = fc_b[e];
        for (int c = 0; c < C; ++c) s += pooled[b * C + c] * fc_w[e * C + c];
        rw[idx] = 1.f / (1.f + expf(-s));
    }
}

// ---------------------------------------------------------------------------
// Per-channel scale/shift for both BN layers: y = acc*sc + sh, then ReLU.
// sc = g*rsqrt(v+eps); sh = (bias - m)*sc + b
// ---------------------------------------------------------------------------
__global__ void scsh_kernel(const float* b1, const float* g1, const float* bb1,
                            const float* m1, const float* v1,
                            const float* b2, const float* g2, const float* bb2,
                            const float* m2, const float* v2,
                            float* scsh1, float* scsh2) {
    int t = threadIdx.x;
    if (t < 128) {
        float sc = g1[t] * rsqrtf(v1[t] + BN_EPS);
        scsh1[t] = sc;
        scsh1[128 + t] = (b1[t] - m1[t]) * sc + bb1[t];
    } else {
        int c = t - 128;
        float sc = g2[c] * rsqrtf(v2[c] + BN_EPS);
        scsh2[c] = sc;
        scsh2[128 + c] = (b2[c] - m2[c]) * sc + bb2[c];
    }
}

// ---------------------------------------------------------------------------
// Mixed weights: wmix[b][tap][co][ci] (bf16) = sum_e rw[b,e] * w[e][co][ci][tap]
// One block per co; w slice (3*CIN*9 floats) is L1-resident across the b loop.
// ---------------------------------------------------------------------------
template <int CIN>
__global__ void mix_kernel(const float* __restrict__ w, const float* __restrict__ rw,
                           ushort* __restrict__ wmix) {
    const int co = blockIdx.x;  // 0..127
    for (int b = 0; b < 16; ++b) {
        const float r0 = rw[b * 3 + 0], r1 = rw[b * 3 + 1], r2 = rw[b * 3 + 2];
        for (int idx = threadIdx.x; idx < CIN * 9; idx += 256) {
            const int ci = idx & (CIN - 1);
            const int tap = idx / CIN;
            const size_t o = ((size_t)co * CIN + ci) * 9 + tap;
            const float m = r0 * w[o]
                          + r1 * w[o + (size_t)128 * CIN * 9]
                          + r2 * w[o + (size_t)2 * 128 * CIN * 9];
            wmix[(((size_t)b * 9 + tap) * 128 + co) * CIN + ci] = f2bf(m);
        }
    }
}

// ---------------------------------------------------------------------------
// x fp32 NCHW [16][64][128][128] -> xT bf16 NHWC [16][128*128][64]
// ---------------------------------------------------------------------------
__global__ void nchw_to_nhwc_kernel(const float* __restrict__ x, ushort* __restrict__ xT) {
    __shared__ float t[64][65];
    const int b = blockIdx.y;
    const int p0 = blockIdx.x * 64;
    const int tid = threadIdx.x;
#pragma unroll
    for (int it = 0; it < 16; ++it) {
        const int idx = it * 256 + tid;
        const int ci = idx >> 6, p = idx & 63;
        t[ci][p] = x[((size_t)b * 64 + ci) * 16384 + p0 + p];
    }
    __syncthreads();
#pragma unroll
    for (int it = 0; it < 2; ++it) {
        const int p = it * 32 + (tid >> 3);
        const int c0 = (tid & 7) * 8;
        ushort8v u;
#pragma unroll
        for (int j = 0; j < 8; ++j) u[j] = f2bf(t[c0 + j][p]);
        *(ushort8v*)&xT[((size_t)b * 16384 + p0 + p) * 64 + c0] = u;
    }
}

// ---------------------------------------------------------------------------
// Pooling of hT (bf16 NHWC, Cout=128): stage A partial sums over 256-px slices
// ---------------------------------------------------------------------------
__global__ void pool2a_kernel(const ushort* __restrict__ hT, float* __restrict__ part) {
    const int b = blockIdx.x, s = blockIdx.y;  // (16, 64)
    const int c2 = threadIdx.x & 63;
    const int g = threadIdx.x >> 6;
    float s0 = 0.f, s1 = 0.f;
    const ushort* base = hT + ((size_t)b * 16384 + s * 256 + g * 64) * 128 + c2 * 2;
    for (int i = 0; i < 64; ++i) {
        const uint v = *(const uint*)(base + (size_t)i * 128);
        s0 += bf2f((ushort)(v & 0xffffu));
        s1 += bf2f((ushort)(v >> 16));
    }
    __shared__ float sp[4][128];
    sp[g][c2 * 2] = s0;
    sp[g][c2 * 2 + 1] = s1;
    __syncthreads();
    if (threadIdx.x < 128) {
        const int c = threadIdx.x;
        part[((size_t)b * 64 + s) * 128 + c] = sp[0][c] + sp[1][c] + sp[2][c] + sp[3][c];
    }
}

// stage B: finish mean, then routing for layer 2 within the same block
__global__ void pool2b_route2_kernel(const float* __restrict__ part,
                                     const float* __restrict__ fcw,
                                     const float* __restrict__ fcb,
                                     float* __restrict__ rw2) {
    const int b = blockIdx.x;  // 16 blocks, 128 threads
    const int c = threadIdx.x;
    float s = 0.f;
    for (int k = 0; k < 64; ++k) s += part[((size_t)b * 64 + k) * 128 + c];
    __shared__ float sp[128];
    sp[c] = s * (1.f / 16384.f);
    __syncthreads();
    if (c < 3) {
        float d = fcb[c];
        for (int k = 0; k < 128; ++k) d += sp[k] * fcw[c * 128 + k];
        rw2[b * 3 + c] = 1.f / (1.f + expf(-d));
    }
}

// ---------------------------------------------------------------------------
// MFMA implicit-GEMM conv3x3(pad1) + fused bias/BN/ReLU.
//   xT  : bf16 NHWC [16][128][128][CIN]
//   wmix: bf16 [16][9][128][CIN]
//   out : fp32 NCHW (layer 2)  OR  bf16 NHWC (layer 1, feeds next layer)
// Block: 256 thr = 4 waves (2x2), tile = 128 co x 128 px (one image row).
// K loop: CIN/32 chunks x 9 taps, one mfma_f32_16x16x32_bf16 per (mf,nf).
// Input halo tile [3][144 cols][32 ci] staged via global_load_lds_dwordx4
// (linear LDS dest; OOB lanes read a zeroed page -> implicit zero padding).
// ---------------------------------------------------------------------------
template <int CIN, bool TO_BF16>
__global__ __launch_bounds__(256)
void conv_mfma_kernel(const ushort* __restrict__ xT, const ushort* __restrict__ wmix,
                      const float* __restrict__ scsh,
                      float* __restrict__ outf, ushort* __restrict__ outh,
                      const ushort* __restrict__ zp) {
    constexpr int NCC = CIN / 32;
    __shared__ short lds[3 * 144 * 32];  // 27648 B

    const int b = blockIdx.z;
    const int h0 = blockIdx.x;
    const int tid = threadIdx.x;
    const int lane = tid & 63, wid = tid >> 6;
    const int wm = wid >> 1, wn = wid & 1;
    const int l15 = lane & 15, lg = lane >> 4;

    f32x4 acc[4][4];
#pragma unroll
    for (int i = 0; i < 4; ++i)
#pragma unroll
        for (int j = 0; j < 4; ++j) acc[i][j] = {0.f, 0.f, 0.f, 0.f};

    const ushort* xTb = xT + (size_t)b * 16384 * CIN;
    const ushort* wb = wmix + (size_t)b * 9 * 128 * CIN;

    for (int cc = 0; cc < NCC; ++cc) {
        const int ci0 = cc * 32;
        // ---- stage [3][144][32] bf16 tile (1728 16B-slots = 27 wave-instrs) ----
        for (int j = wid; j < 27; j += 4) {
            const int r = j / 9;              // tile row 0..2
            const int ws = (j - r * 9) * 64 + lane;
            const int c = ws >> 2;            // 0..143 (130..143 junk -> zp)
            const int g = ws & 3;             // ci subgroup of 8
            const int hg = h0 - 1 + r;
            const int wg = c - 1;
            const ushort* src = zp;
            if ((unsigned)hg < 128u && (unsigned)wg < 128u)
                src = xTb + ((size_t)(hg * 128 + wg)) * CIN + ci0 + g * 8;
            __builtin_amdgcn_global_load_lds(
                (const __attribute__((address_space(1))) void*)src,
                (__attribute__((address_space(3))) void*)&lds[j * 512],
                16, 0, 0);
        }
        __syncthreads();

#pragma unroll
        for (int tap = 0; tap < 9; ++tap) {
            const int dy = tap / 3, dx = tap % 3;
            bf16x8 af[4];
#pragma unroll
            for (int mf = 0; mf < 4; ++mf) {
                const int co = wm * 64 + mf * 16 + l15;
                af[mf] = *(const bf16x8*)&wb[((size_t)tap * 128 + co) * CIN + ci0 + lg * 8];
            }
            bf16x8 bfr[4];
#pragma unroll
            for (int nf = 0; nf < 4; ++nf) {
                const int px = wn * 64 + nf * 16 + l15;
                const int c = px + dx;
                bfr[nf] = *(const bf16x8*)&lds[((dy * 144 + c) * 4 + lg) * 8];
            }
#pragma unroll
            for (int mf = 0; mf < 4; ++mf)
#pragma unroll
                for (int nf = 0; nf < 4; ++nf)
                    acc[mf][nf] = __builtin_amdgcn_mfma_f32_16x16x32_bf16(
                        af[mf], bfr[nf], acc[mf][nf], 0, 0, 0);
        }
        __syncthreads();
    }

    // ---- epilogue: y = relu(acc*sc + sh) ----
#pragma unroll
    for (int mf = 0; mf < 4; ++mf) {
        const int co0 = wm * 64 + mf * 16 + lg * 4;  // 4 consecutive co per lane
        const f32x4 sc = *(const f32x4*)&scsh[co0];
        const f32x4 sh = *(const f32x4*)&scsh[128 + co0];
#pragma unroll
        for (int nf = 0; nf < 4; ++nf) {
            const int px = wn * 64 + nf * 16 + l15;
            float v[4];
#pragma unroll
            for (int r = 0; r < 4; ++r) {
                float y = fmaf(acc[mf][nf][r], sc[r], sh[r]);
                v[r] = y > 0.f ? y : 0.f;
            }
            if (TO_BF16) {
                uint2 pk;
                pk.x = (uint)f2bf(v[0]) | ((uint)f2bf(v[1]) << 16);
                pk.y = (uint)f2bf(v[2]) | ((uint)f2bf(v[3]) << 16);
                *(uint2*)&outh[((size_t)b * 16384 + h0 * 128 + px) * 128 + co0] = pk;
            } else {
#pragma unroll
                for (int r = 0; r < 4; ++r)
                    outf[((size_t)(b * 128 + co0 + r)) * 16384 + h0 * 128 + px] = v[r];
            }
        }
    }
}

// ---------------------------------------------------------------------------
extern "C" void kernel_launch(void* const* d_in, const int* in_sizes, int n_in,
                              void* d_out, int out_size, void* d_ws, size_t ws_size,
                              hipStream_t stream) {
    const float* x     = (const float*)d_in[0];
    const float* w1    = (const float*)d_in[1];
    const float* b1    = (const float*)d_in[2];
    const float* fc1_w = (const float*)d_in[3];
    const float* fc1_b = (const float*)d_in[4];
    const float* bn1g  = (const float*)d_in[5];
    const float* bn1b  = (const float*)d_in[6];
    const float* bn1m  = (const float*)d_in[7];
    const float* bn1v  = (const float*)d_in[8];
    const float* w2    = (const float*)d_in[9];
    const float* b2    = (const float*)d_in[10];
    const float* fc2_w = (const float*)d_in[11];
    const float* fc2_b = (const float*)d_in[12];
    const float* bn2g  = (const float*)d_in[13];
    const float* bn2b  = (const float*)d_in[14];
    const float* bn2m  = (const float*)d_in[15];
    const float* bn2v  = (const float*)d_in[16];

    float* out = (float*)d_out;
    char* ws = (char*)d_ws;

    // workspace layout (bytes)
    ushort* hT    = (ushort*)(ws + 0);            //  67,108,864 B
    ushort* xT    = (ushort*)(ws + 67108864);     //  33,554,432 B
    ushort* wmix1 = (ushort*)(ws + 100663296);    //   2,359,296 B
    ushort* wmix2 = (ushort*)(ws + 103022592);    //   4,718,592 B
    float*  part  = (float*) (ws + 107741184);    //     524,288 B
    float*  pool1 = (float*) (ws + 108265472);    //       4,096 B
    float*  rw1   = (float*) (ws + 108269568);    //         192 B
    float*  rw2   = (float*) (ws + 108269760);    //         192 B
    float*  scsh1 = (float*) (ws + 108269952);    //       1,024 B
    float*  scsh2 = (float*) (ws + 108270976);    //       1,024 B
    ushort* zp    = (ushort*)(ws + 108272000);    //          64 B (zero page)

    hipMemsetAsync(zp, 0, 64, stream);

    scsh_kernel<<<1, 256, 0, stream>>>(b1, bn1g, bn1b, bn1m, bn1v,
                                       b2, bn2g, bn2b, bn2m, bn2v, scsh1, scsh2);

    // ---- layer 1 ----
    pool_kernel<<<16 * 64, 256, 0, stream>>>(x, pool1);
    route_kernel<<<1, 64, 0, stream>>>(pool1, fc1_w, fc1_b, rw1, 64);
    mix_kernel<64><<<128, 256, 0, stream>>>(w1, rw1, wmix1);
    nchw_to_nhwc_kernel<<<dim3(256, 16), 256, 0, stream>>>(x, xT);
    conv_mfma_kernel<64, true><<<dim3(128, 1, 16), 256, 0, stream>>>(
        xT, wmix1, scsh1, nullptr, hT, zp);

    // ---- layer 2 ----
    pool2a_kernel<<<dim3(16, 64), 256, 0, stream>>>(hT, part);
    pool2b_route2_kernel<<<16, 128, 0, stream>>>(part, fc2_w, fc2_b, rw2);
    mix_kernel<128><<<128, 256, 0, stream>>>(w2, rw2, wmix2);
    conv_mfma_kernel<128, false><<<dim3(128, 1, 16), 256, 0, stream>>>(
        hT, wmix2, scsh2, out, nullptr, zp);
}